// Round 2
// baseline (354.140 us; speedup 1.0000x reference)
//
#include <hip/hip_runtime.h>

constexpr int N_TOKENS = 16384;
constexpr int D_MODEL  = 2048;

// One block per token row. 256 threads * 8 floats = 2048 = D_MODEL.
// x row held in registers across {dot-product, scale} so x is read once.
__global__ __launch_bounds__(256) void wbr_kernel(
    const float* __restrict__ x,
    const float* __restrict__ gw,   // (D_MODEL, 2) row-major: gw[2*d + branch]
    const float* __restrict__ gb,   // (2,)
    float* __restrict__ out)        // pre_x then post_x, each N_TOKENS*D_MODEL
{
    const int row = blockIdx.x;
    const int t   = threadIdx.x;
    const size_t rbase = (size_t)row * D_MODEL;
    const float* xr = x + rbase;

    const int i0 = t * 4;           // elems [i0, i0+4)
    const int i1 = 1024 + t * 4;    // elems [i1, i1+4)

    const float4 xa = *reinterpret_cast<const float4*>(xr + i0);
    const float4 xb = *reinterpret_cast<const float4*>(xr + i1);

    // gate_w rows for those d's (interleaved branch0/branch1)
    const float4 wa0 = *reinterpret_cast<const float4*>(gw + 2 * i0);
    const float4 wa1 = *reinterpret_cast<const float4*>(gw + 2 * i0 + 4);
    const float4 wb0 = *reinterpret_cast<const float4*>(gw + 2 * i1);
    const float4 wb1 = *reinterpret_cast<const float4*>(gw + 2 * i1 + 4);

    // f64 partial dots: exact sign for the mask decision (threshold at z==0)
    double d0 = (double)xa.x * wa0.x + (double)xa.y * wa0.z
              + (double)xa.z * wa1.x + (double)xa.w * wa1.z
              + (double)xb.x * wb0.x + (double)xb.y * wb0.z
              + (double)xb.z * wb1.x + (double)xb.w * wb1.z;
    double d1 = (double)xa.x * wa0.y + (double)xa.y * wa0.w
              + (double)xa.z * wa1.y + (double)xa.w * wa1.w
              + (double)xb.x * wb0.y + (double)xb.y * wb0.w
              + (double)xb.z * wb1.y + (double)xb.w * wb1.w;

    // wave64 reduction
    #pragma unroll
    for (int off = 32; off > 0; off >>= 1) {
        d0 += __shfl_down(d0, off);
        d1 += __shfl_down(d1, off);
    }

    __shared__ double sred[4][2];
    __shared__ float  scl[2];
    const int wid = t >> 6;
    if ((t & 63) == 0) { sred[wid][0] = d0; sred[wid][1] = d1; }
    __syncthreads();
    if (t == 0) {
        const double z0 = sred[0][0] + sred[1][0] + sred[2][0] + sred[3][0] + (double)gb[0];
        const double z1 = sred[0][1] + sred[1][1] + sred[2][1] + sred[3][1] + (double)gb[1];
        const int m0 = z0 > 0.0;
        const int m1 = z1 > 0.0;
        const float s0 = m0 ? (float)(1.0 / (1.0 + exp(-z0))) : 0.0f;
        const float s1 = m1 ? (float)(1.0 / (1.0 + exp(-z1))) : 0.0f;
        const float a = s0 + s1;                 // pre_x scale
        scl[0] = a;
        scl[1] = (float)(m0 + m1) * a;           // post_x scale
    }
    __syncthreads();
    const float a = scl[0];
    const float b = scl[1];

    float* pre  = out + rbase;
    float* post = out + (size_t)N_TOKENS * D_MODEL + rbase;

    *reinterpret_cast<float4*>(pre + i0)  = make_float4(xa.x * a, xa.y * a, xa.z * a, xa.w * a);
    *reinterpret_cast<float4*>(pre + i1)  = make_float4(xb.x * a, xb.y * a, xb.z * a, xb.w * a);
    *reinterpret_cast<float4*>(post + i0) = make_float4(xa.x * b, xa.y * b, xa.z * b, xa.w * b);
    *reinterpret_cast<float4*>(post + i1) = make_float4(xb.x * b, xb.y * b, xb.z * b, xb.w * b);
}

extern "C" void kernel_launch(void* const* d_in, const int* in_sizes, int n_in,
                              void* d_out, int out_size, void* d_ws, size_t ws_size,
                              hipStream_t stream) {
    const float* x  = (const float*)d_in[0];
    const float* gw = (const float*)d_in[1];
    const float* gb = (const float*)d_in[2];
    float* out = (float*)d_out;
    wbr_kernel<<<N_TOKENS, 256, 0, stream>>>(x, gw, gb, out);
}